// Round 2
// baseline (117.138 us; speedup 1.0000x reference)
//
#include <hip/hip_runtime.h>
#include <hip/hip_bf16.h>

// Volume-rendering composite:
//   dd = deltas * density                       [rays, 128]
//   T_i = exp(-sum_{j<i} dd_j)                  (exclusive cumsum)
//   w_i = (1 - exp(-dd_i)) * T_i = T_i - T_{i+1}
//   out[r, c] = sum_i w_i * rgb[r, i, c]        [rays, 3]
//
// Wave = 2 rays: lanes 0-31 own ray A, lanes 32-63 ray B. Segment-lane l
// owns samples 4l..4l+3, so every global load is an aligned 16B dwordx4:
//   density/deltas: 1 float4 each; rgb: 3 float4 (12 floats = 4 samples x rgb).
// Scan: segmented __shfl_up over 32 lanes. Reduce: __shfl_xor (16..1) —
// xor with offsets <32 never crosses the 32-lane segment boundary.

__global__ __launch_bounds__(256) void composite_kernel(
    const float4* __restrict__ rgb4,     // [rays * 96]  (rays,128,3) as float4
    const float4* __restrict__ density4, // [rays * 32]
    const float4* __restrict__ deltas4,  // [rays * 32]
    float* __restrict__ out,             // [rays, 3]
    int num_rays)
{
    const int lane = threadIdx.x & 63;
    const int seg  = lane >> 5;                       // 0 or 1: which ray of the wave
    const int sl   = lane & 31;                       // segment-local lane
    const int wave = threadIdx.x >> 6;                // 0..3
    const int ray  = (blockIdx.x * 4 + wave) * 2 + seg;
    if (ray >= num_rays) return;

    // --- density/deltas: lane owns samples 4sl..4sl+3 ---
    const float4 de = density4[(size_t)ray * 32 + sl];
    const float4 dl = deltas4 [(size_t)ray * 32 + sl];
    const float dd0 = de.x * dl.x;
    const float dd1 = de.y * dl.y;
    const float dd2 = de.z * dl.z;
    const float dd3 = de.w * dl.w;
    const float local = dd0 + dd1 + dd2 + dd3;

    // --- segmented inclusive scan of per-lane sums (32-lane segment) ---
    float s = local;
#pragma unroll
    for (int off = 1; off < 32; off <<= 1) {
        float v = __shfl_up(s, off, 64);   // src = lane - off, stays in segment when sl >= off
        if (sl >= off) s += v;
    }
    const float excl = s - local;          // sum of dd over samples < 4*sl
    const float c0 = excl + dd0;
    const float c1 = c0 + dd1;
    const float c2 = c1 + dd2;
    const float c3 = c2 + dd3;

    const float Te = __expf(-excl);
    const float T0 = __expf(-c0);
    const float T1 = __expf(-c1);
    const float T2 = __expf(-c2);
    const float T3 = __expf(-c3);
    const float w0 = Te - T0;
    const float w1 = T0 - T1;
    const float w2 = T1 - T2;
    const float w3 = T2 - T3;

    // --- rgb: lane reads floats [12sl, 12sl+12) of its ray = 3 aligned float4 ---
    const float4* r4 = rgb4 + (size_t)ray * 96 + sl * 3;
    const float4 q0 = r4[0];   // r0 g0 b0 r1
    const float4 q1 = r4[1];   // g1 b1 r2 g2
    const float4 q2 = r4[2];   // b2 r3 g3 b3

    float rr = w0 * q0.x + w1 * q0.w + w2 * q1.z + w3 * q2.y;
    float gg = w0 * q0.y + w1 * q1.x + w2 * q1.w + w3 * q2.z;
    float bb = w0 * q0.z + w1 * q1.y + w2 * q2.x + w3 * q2.w;

    // --- segment reduce (xor butterfly stays within the 32-lane segment) ---
#pragma unroll
    for (int off = 16; off; off >>= 1) {
        rr += __shfl_xor(rr, off, 64);
        gg += __shfl_xor(gg, off, 64);
        bb += __shfl_xor(bb, off, 64);
    }

    if (sl == 0) {
        float* o = out + (size_t)ray * 3;
        o[0] = rr;
        o[1] = gg;
        o[2] = bb;
    }
}

extern "C" void kernel_launch(void* const* d_in, const int* in_sizes, int n_in,
                              void* d_out, int out_size, void* d_ws, size_t ws_size,
                              hipStream_t stream) {
    const float4* rgb     = (const float4*)d_in[0];
    const float4* density = (const float4*)d_in[1];
    const float4* deltas  = (const float4*)d_in[2];
    float* out = (float*)d_out;

    const int num_rays = in_sizes[1] / 128;            // 262144
    const int rays_per_block = 8;                      // 4 waves x 2 rays
    const int grid = (num_rays + rays_per_block - 1) / rays_per_block;

    composite_kernel<<<grid, 256, 0, stream>>>(rgb, density, deltas, out, num_rays);
}